// Round 2
// baseline (888.002 us; speedup 1.0000x reference)
//
#include <hip/hip_runtime.h>
#include <hip/hip_bf16.h>

#define WW 128
#define GG 64
#define GN_EPS 1e-5f

typedef __attribute__((ext_vector_type(8))) short short8;
typedef __attribute__((ext_vector_type(4))) float floatx4;

__device__ inline short f2bf(float f) {
    __hip_bfloat16 h = __float2bfloat16(f);
    return __builtin_bit_cast(short, h);
}
__device__ inline float bf2f(__hip_bfloat16 h) { return __bfloat162float(h); }

// ---------------- GraphNorm stats: per-graph sum, sumsq, count ----------------
// block = 128 threads (one per channel), each block handles a 64-row chunk.
// batch_map is sorted, so each chunk spans ~1-2 segments -> few atomic flushes.
__global__ __launch_bounds__(128) void stats_kernel(
    const float* __restrict__ x, const int* __restrict__ batch, int N,
    float* __restrict__ gsum, float* __restrict__ gsumsq, float* __restrict__ gcnt)
{
    int w = threadIdx.x;
    int row0 = blockIdx.x * 64;
    int row1 = min(row0 + 64, N);
    float s = 0.f, ss = 0.f;
    int cur = batch[row0];
    int cnt = 0;
    for (int i = row0; i < row1; ++i) {
        int g = batch[i];
        if (g != cur) {
            atomicAdd(&gsum[cur * WW + w], s);
            atomicAdd(&gsumsq[cur * WW + w], ss);
            if (w == 0) atomicAdd(&gcnt[cur], (float)cnt);
            s = 0.f; ss = 0.f; cnt = 0; cur = g;
        }
        float v = x[(size_t)i * WW + w];
        s += v; ss += v * v; ++cnt;
    }
    atomicAdd(&gsum[cur * WW + w], s);
    atomicAdd(&gsumsq[cur * WW + w], ss);
    if (w == 0) atomicAdd(&gcnt[cur], (float)cnt);
}

// ---------------- fold stats into per-(g,w) affine scale/shift ----------------
// out = x - ms*mean ; var = Sxx/n - mean^2 * ms * (2 - ms)
// xn = wgt*out/std + bias = scale*x + shift
__global__ __launch_bounds__(256) void finalize_kernel(
    const float* __restrict__ gsum, const float* __restrict__ gsumsq,
    const float* __restrict__ gcnt,
    const float* __restrict__ wgt, const float* __restrict__ bias,
    const float* __restrict__ ms,
    float* __restrict__ scalev, float* __restrict__ shiftv)
{
    int idx = blockIdx.x * blockDim.x + threadIdx.x;
    if (idx >= GG * WW) return;
    int g = idx >> 7, w = idx & (WW - 1);
    float cnt = gcnt[g];
    float inv = cnt > 0.f ? 1.f / cnt : 0.f;
    float mean = gsum[idx] * inv;
    float msw = ms[w];
    float var = gsumsq[idx] * inv - mean * mean * msw * (2.f - msw);
    var = fmaxf(var, 0.f);
    float sc = wgt[w] * rsqrtf(var + GN_EPS);
    scalev[idx] = sc;
    shiftv[idx] = bias[w] - sc * msw * mean;
}

// ---------------- normalize: xn = scale*x + shift (bf16 out) ----------------
__global__ __launch_bounds__(256) void normalize_kernel(
    const float* __restrict__ x, const int* __restrict__ batch,
    const float* __restrict__ scalev, const float* __restrict__ shiftv,
    __hip_bfloat16* __restrict__ xn, int N)
{
    size_t tid = (size_t)blockIdx.x * blockDim.x + threadIdx.x;
    if (tid >= (size_t)N * WW) return;
    int row = (int)(tid >> 7);
    int w = (int)(tid & (WW - 1));
    int g = batch[row];
    float v = x[tid];
    xn[tid] = __float2bfloat16(scalev[g * WW + w] * v + shiftv[g * WW + w]);
}

// ---------------- convert fp32 weight matrices -> bf16 ----------------
__global__ __launch_bounds__(256) void cvt_w_kernel(
    const float* __restrict__ w0, const float* __restrict__ w1,
    const float* __restrict__ w2, const float* __restrict__ w3,
    __hip_bfloat16* __restrict__ dst)
{
    int idx = blockIdx.x * blockDim.x + threadIdx.x;   // 0 .. 4*16384-1
    int m = idx >> 14;
    int o = idx & 16383;
    const float* src = (m == 0) ? w0 : (m == 1) ? w1 : (m == 2) ? w2 : w3;
    dst[idx] = __float2bfloat16(src[o]);
}

// ---------------- scatter: agg[dst] += ew * feat[src] ----------------
__global__ __launch_bounds__(256) void scatter_kernel(
    const __hip_bfloat16* __restrict__ feat, const int* __restrict__ ei,
    const float* __restrict__ ew, float* __restrict__ agg, int E)
{
    size_t t = (size_t)blockIdx.x * blockDim.x + threadIdx.x;
    int e = (int)(t >> 7);
    int w = (int)(t & (WW - 1));
    if (e >= E) return;
    int src = ei[e];
    int dst = ei[(size_t)E + e];
    float wt = ew[e];
    float v = bf2f(feat[(size_t)src * WW + w]);
    atomicAdd(&agg[(size_t)dst * WW + w], wt * v);
}

// ---------------- fused GEMM: out = act([A1|A2] @ [Wrel;Wroot]^T + b) (+resid) ----------
// A1 = agg (f32, N x 128), A2 = xn/y1 (bf16, N x 128). K = 256 total.
// Per block: 4 waves, one 16-row stripe each; 8 col-tiles of 16; 8 k-chunks of 32.
// B fragment == row-major read of W (y = A @ W^T): lane reads
// W[16t + (lane&15)][koff .. koff+7]. A frag: A[row0+(lane&15)][koff..koff+7].
// C/D: col = lane&15, row = (lane>>4)*4 + reg (m89-verified layout).
template <bool OUT_BF16>
__global__ __launch_bounds__(256) void gemm_kernel(
    const float* __restrict__ A1, const __hip_bfloat16* __restrict__ A2,
    const __hip_bfloat16* __restrict__ Wrel, const __hip_bfloat16* __restrict__ Wroot,
    const float* __restrict__ bias, const float* __restrict__ resid,
    void* __restrict__ outv, int N, int leaky)
{
    int wave = threadIdx.x >> 6;
    int lane = threadIdx.x & 63;
    int q = lane >> 4;
    int r16 = lane & 15;
    int row0 = (blockIdx.x * 4 + wave) * 16;
    if (row0 >= N) return;

    int arow = row0 + r16;
    int ar = arow < N ? arow : N - 1;   // clamp loads; stores masked below

    floatx4 acc[8];
#pragma unroll
    for (int t = 0; t < 8; ++t) acc[t] = (floatx4){0.f, 0.f, 0.f, 0.f};

#pragma unroll
    for (int kc = 0; kc < 8; ++kc) {
        int koff = (kc & 3) * 32 + q * 8;
        size_t abase = (size_t)ar * WW + koff;
        short8 afrag;
        if (kc < 4) {
            const floatx4* ap = (const floatx4*)(A1 + abase);
            floatx4 a0 = ap[0];
            floatx4 a1 = ap[1];
            afrag[0] = f2bf(a0[0]); afrag[1] = f2bf(a0[1]);
            afrag[2] = f2bf(a0[2]); afrag[3] = f2bf(a0[3]);
            afrag[4] = f2bf(a1[0]); afrag[5] = f2bf(a1[1]);
            afrag[6] = f2bf(a1[2]); afrag[7] = f2bf(a1[3]);
        } else {
            afrag = *(const short8*)(A2 + abase);
        }
        const __hip_bfloat16* Wsel = (kc < 4) ? Wrel : Wroot;
#pragma unroll
        for (int t = 0; t < 8; ++t) {
            short8 bfrag = *(const short8*)(Wsel + ((size_t)(t * 16 + r16) * WW + koff));
            acc[t] = __builtin_amdgcn_mfma_f32_16x16x32_bf16(afrag, bfrag, acc[t], 0, 0, 0);
        }
    }

#pragma unroll
    for (int t = 0; t < 8; ++t) {
        int col = t * 16 + r16;
        float b = bias[col];
#pragma unroll
        for (int rr = 0; rr < 4; ++rr) {
            int row = row0 + q * 4 + rr;
            if (row < N) {
                float v = acc[t][rr] + b;
                if (leaky) v = v >= 0.f ? v : 0.1f * v;
                if (resid) v += resid[(size_t)row * WW + col];
                if (OUT_BF16)
                    ((__hip_bfloat16*)outv)[(size_t)row * WW + col] = __float2bfloat16(v);
                else
                    ((float*)outv)[(size_t)row * WW + col] = v;
            }
        }
    }
}

extern "C" void kernel_launch(void* const* d_in, const int* in_sizes, int n_in,
                              void* d_out, int out_size, void* d_ws, size_t ws_size,
                              hipStream_t stream) {
    const float* x      = (const float*)d_in[0];
    const int*   ei     = (const int*)d_in[1];
    const float* ew     = (const float*)d_in[2];
    const int*   batch  = (const int*)d_in[3];
    const float* gnw    = (const float*)d_in[4];
    const float* gnb    = (const float*)d_in[5];
    const float* gnm    = (const float*)d_in[6];
    const float* Wrel1  = (const float*)d_in[7];
    const float* brel1  = (const float*)d_in[8];
    const float* Wroot1 = (const float*)d_in[9];
    const float* Wrel2  = (const float*)d_in[10];
    const float* brel2  = (const float*)d_in[11];
    const float* Wroot2 = (const float*)d_in[12];

    int N = in_sizes[0] / WW;
    int E = in_sizes[1] / 2;

    // workspace layout: agg(f32 N*W) | xn(bf16 N*W) | y1(bf16 N*W) | Wb(bf16 4*W*W) | stats
    float* agg = (float*)d_ws;
    __hip_bfloat16* xn = (__hip_bfloat16*)(agg + (size_t)N * WW);
    __hip_bfloat16* y1 = xn + (size_t)N * WW;
    __hip_bfloat16* Wb = y1 + (size_t)N * WW;       // [Wrel1|Wroot1|Wrel2|Wroot2]
    float* gsum   = (float*)(Wb + 4 * WW * WW);
    float* gsumsq = gsum + GG * WW;
    float* gcnt   = gsumsq + GG * WW;               // GG floats
    float* scalev = gcnt + GG;
    float* shiftv = scalev + GG * WW;

    hipMemsetAsync(gsum, 0, (size_t)(2 * GG * WW + GG) * sizeof(float), stream);
    hipMemsetAsync(agg, 0, (size_t)N * WW * sizeof(float), stream);

    cvt_w_kernel<<<(4 * WW * WW) / 256, 256, 0, stream>>>(Wrel1, Wroot1, Wrel2, Wroot2, Wb);
    stats_kernel<<<(N + 63) / 64, 128, 0, stream>>>(x, batch, N, gsum, gsumsq, gcnt);
    finalize_kernel<<<(GG * WW + 255) / 256, 256, 0, stream>>>(
        gsum, gsumsq, gcnt, gnw, gnb, gnm, scalev, shiftv);
    normalize_kernel<<<(int)(((size_t)N * WW + 255) / 256), 256, 0, stream>>>(
        x, batch, scalev, shiftv, xn, N);

    scatter_kernel<<<(int)(((size_t)E * WW + 255) / 256), 256, 0, stream>>>(
        xn, ei, ew, agg, E);
    gemm_kernel<true><<<(N + 63) / 64, 256, 0, stream>>>(
        agg, xn, Wb, Wb + WW * WW, brel1, nullptr, y1, N, 1);

    hipMemsetAsync(agg, 0, (size_t)N * WW * sizeof(float), stream);
    scatter_kernel<<<(int)(((size_t)E * WW + 255) / 256), 256, 0, stream>>>(
        y1, ei, ew, agg, E);
    gemm_kernel<false><<<(N + 63) / 64, 256, 0, stream>>>(
        agg, y1, Wb + 2 * WW * WW, Wb + 3 * WW * WW, brel2, x, d_out, N, 0);
}

// Round 3
// 533.229 us; speedup vs baseline: 1.6653x; 1.6653x over previous
//
#include <hip/hip_runtime.h>
#include <hip/hip_bf16.h>

#define WW 128
#define GG 64
#define GN_EPS 1e-5f
#define SCAN_B 1024

typedef __attribute__((ext_vector_type(8))) short short8;
typedef __attribute__((ext_vector_type(4))) float floatx4;

__device__ inline short f2bf(float f) {
    __hip_bfloat16 h = __float2bfloat16(f);
    return __builtin_bit_cast(short, h);
}
__device__ inline float bf2f(__hip_bfloat16 h) { return __bfloat162float(h); }

// ---------------- GraphNorm stats: per-graph sum, sumsq, count ----------------
__global__ __launch_bounds__(128) void stats_kernel(
    const float* __restrict__ x, const int* __restrict__ batch, int N,
    float* __restrict__ gsum, float* __restrict__ gsumsq, float* __restrict__ gcnt)
{
    int w = threadIdx.x;
    int row0 = blockIdx.x * 64;
    int row1 = min(row0 + 64, N);
    float s = 0.f, ss = 0.f;
    int cur = batch[row0];
    int cnt = 0;
    for (int i = row0; i < row1; ++i) {
        int g = batch[i];
        if (g != cur) {
            atomicAdd(&gsum[cur * WW + w], s);
            atomicAdd(&gsumsq[cur * WW + w], ss);
            if (w == 0) atomicAdd(&gcnt[cur], (float)cnt);
            s = 0.f; ss = 0.f; cnt = 0; cur = g;
        }
        float v = x[(size_t)i * WW + w];
        s += v; ss += v * v; ++cnt;
    }
    atomicAdd(&gsum[cur * WW + w], s);
    atomicAdd(&gsumsq[cur * WW + w], ss);
    if (w == 0) atomicAdd(&gcnt[cur], (float)cnt);
}

// ---------------- fold stats into per-(g,w) affine scale/shift ----------------
__global__ __launch_bounds__(256) void finalize_kernel(
    const float* __restrict__ gsum, const float* __restrict__ gsumsq,
    const float* __restrict__ gcnt,
    const float* __restrict__ wgt, const float* __restrict__ bias,
    const float* __restrict__ ms,
    float* __restrict__ scalev, float* __restrict__ shiftv)
{
    int idx = blockIdx.x * blockDim.x + threadIdx.x;
    if (idx >= GG * WW) return;
    int g = idx >> 7, w = idx & (WW - 1);
    float cnt = gcnt[g];
    float inv = cnt > 0.f ? 1.f / cnt : 0.f;
    float mean = gsum[idx] * inv;
    float msw = ms[w];
    float var = gsumsq[idx] * inv - mean * mean * msw * (2.f - msw);
    var = fmaxf(var, 0.f);
    float sc = wgt[w] * rsqrtf(var + GN_EPS);
    scalev[idx] = sc;
    shiftv[idx] = bias[w] - sc * msw * mean;
}

// ---------------- normalize: xn = scale*x + shift (bf16 out) ----------------
__global__ __launch_bounds__(256) void normalize_kernel(
    const float* __restrict__ x, const int* __restrict__ batch,
    const float* __restrict__ scalev, const float* __restrict__ shiftv,
    __hip_bfloat16* __restrict__ xn, int N)
{
    size_t tid = (size_t)blockIdx.x * blockDim.x + threadIdx.x;
    if (tid >= (size_t)N * WW) return;
    int row = (int)(tid >> 7);
    int w = (int)(tid & (WW - 1));
    int g = batch[row];
    float v = x[tid];
    xn[tid] = __float2bfloat16(scalev[g * WW + w] * v + shiftv[g * WW + w]);
}

// ---------------- convert fp32 weight matrices -> bf16 ----------------
__global__ __launch_bounds__(256) void cvt_w_kernel(
    const float* __restrict__ w0, const float* __restrict__ w1,
    const float* __restrict__ w2, const float* __restrict__ w3,
    __hip_bfloat16* __restrict__ dst)
{
    int idx = blockIdx.x * blockDim.x + threadIdx.x;   // 0 .. 4*16384-1
    int m = idx >> 14;
    int o = idx & 16383;
    const float* src = (m == 0) ? w0 : (m == 1) ? w1 : (m == 2) ? w2 : w3;
    dst[idx] = __float2bfloat16(src[o]);
}

// ---------------- CSR build: histogram over dst ----------------
__global__ __launch_bounds__(256) void hist_kernel(
    const int* __restrict__ ei, int E, int* __restrict__ deg)
{
    int e = blockIdx.x * 256 + threadIdx.x;
    if (e < E) atomicAdd(&deg[ei[(size_t)E + e]], 1);
}

// ---------------- hierarchical exclusive scan (3 kernels) ----------------
__global__ __launch_bounds__(SCAN_B) void scan_blocks(
    const int* __restrict__ deg, int N, int* __restrict__ off, int* __restrict__ bsum)
{
    __shared__ int s[SCAN_B];
    int t = threadIdx.x;
    int i = blockIdx.x * SCAN_B + t;
    int v = (i < N) ? deg[i] : 0;
    s[t] = v; __syncthreads();
    for (int d = 1; d < SCAN_B; d <<= 1) {
        int tmp = (t >= d) ? s[t - d] : 0;
        __syncthreads();
        s[t] += tmp;
        __syncthreads();
    }
    if (i < N) off[i] = s[t] - v;                 // block-local exclusive
    if (t == SCAN_B - 1) bsum[blockIdx.x] = s[t]; // block total
}

__global__ __launch_bounds__(256) void scan_partials(int* __restrict__ bsum, int P)
{
    __shared__ int s[256];
    int t = threadIdx.x;
    int v = (t < P) ? bsum[t] : 0;
    s[t] = v; __syncthreads();
    for (int d = 1; d < 256; d <<= 1) {
        int tmp = (t >= d) ? s[t - d] : 0;
        __syncthreads();
        s[t] += tmp;
        __syncthreads();
    }
    if (t < P) bsum[t] = s[t] - v;                // exclusive, in place
}

__global__ __launch_bounds__(SCAN_B) void add_offsets(
    int* __restrict__ off, const int* __restrict__ bsum, int N)
{
    int i = blockIdx.x * SCAN_B + threadIdx.x;
    if (i < N) off[i] += bsum[blockIdx.x];
}

// ---------------- placement: ebuf[slot] = {src, weight} bucketed by dst ------
__global__ __launch_bounds__(256) void place_kernel(
    const int* __restrict__ ei, const float* __restrict__ ew,
    const int* __restrict__ off, int* __restrict__ cursor,
    int2* __restrict__ ebuf, int E)
{
    int e = blockIdx.x * 256 + threadIdx.x;
    if (e >= E) return;
    int dst = ei[(size_t)E + e];
    int slot = off[dst] + atomicAdd(&cursor[dst], 1);
    ebuf[slot] = make_int2(ei[e], __float_as_int(ew[e]));
}

// ---------------- gather: agg[i] = sum_{e: dst=i} ew_e * feat[src_e] ----------
// one wave per node; lane handles 2 channels (bf16x2 loads). No atomics.
__global__ __launch_bounds__(256) void gather_kernel(
    const __hip_bfloat16* __restrict__ feat, const int2* __restrict__ ebuf,
    const int* __restrict__ off, const int* __restrict__ deg,
    __hip_bfloat16* __restrict__ aggbf, int N)
{
    int wave = threadIdx.x >> 6;
    int lane = threadIdx.x & 63;
    int node = blockIdx.x * 4 + wave;
    if (node >= N) return;
    int start = off[node];
    int d = deg[node];
    float ax = 0.f, ay = 0.f;
    for (int k = 0; k < d; ++k) {
        int2 p = ebuf[start + k];                      // broadcast (lane-uniform)
        float wt = __int_as_float(p.y);
        __hip_bfloat162 v = ((const __hip_bfloat162*)(feat + (size_t)p.x * WW))[lane];
        ax += wt * __bfloat162float(v.x);
        ay += wt * __bfloat162float(v.y);
    }
    __hip_bfloat162 o;
    o.x = __float2bfloat16(ax);
    o.y = __float2bfloat16(ay);
    ((__hip_bfloat162*)(aggbf + (size_t)node * WW))[lane] = o;
}

// ---------------- fused GEMM: out = act([A1|A2] @ [Wrel;Wroot]^T + b) (+resid) ----------
// A1 = aggbf (bf16), A2 = xn/y1 (bf16). K = 256 total.
// B fragment == row-major read of W (y = A @ W^T). C/D: col=lane&15, row=quad*4+reg.
template <bool OUT_BF16>
__global__ __launch_bounds__(256) void gemm_kernel(
    const __hip_bfloat16* __restrict__ A1, const __hip_bfloat16* __restrict__ A2,
    const __hip_bfloat16* __restrict__ Wrel, const __hip_bfloat16* __restrict__ Wroot,
    const float* __restrict__ bias, const float* __restrict__ resid,
    void* __restrict__ outv, int N, int leaky)
{
    int wave = threadIdx.x >> 6;
    int lane = threadIdx.x & 63;
    int q = lane >> 4;
    int r16 = lane & 15;
    int row0 = (blockIdx.x * 4 + wave) * 16;
    if (row0 >= N) return;

    int arow = row0 + r16;
    int ar = arow < N ? arow : N - 1;   // clamp loads; stores masked below

    floatx4 acc[8];
#pragma unroll
    for (int t = 0; t < 8; ++t) acc[t] = (floatx4){0.f, 0.f, 0.f, 0.f};

#pragma unroll
    for (int kc = 0; kc < 8; ++kc) {
        int koff = (kc & 3) * 32 + q * 8;
        const __hip_bfloat16* Asel = (kc < 4) ? A1 : A2;
        const __hip_bfloat16* Wsel = (kc < 4) ? Wrel : Wroot;
        short8 afrag = *(const short8*)(Asel + ((size_t)ar * WW + koff));
#pragma unroll
        for (int t = 0; t < 8; ++t) {
            short8 bfrag = *(const short8*)(Wsel + ((size_t)(t * 16 + r16) * WW + koff));
            acc[t] = __builtin_amdgcn_mfma_f32_16x16x32_bf16(afrag, bfrag, acc[t], 0, 0, 0);
        }
    }

#pragma unroll
    for (int t = 0; t < 8; ++t) {
        int col = t * 16 + r16;
        float b = bias[col];
#pragma unroll
        for (int rr = 0; rr < 4; ++rr) {
            int row = row0 + q * 4 + rr;
            if (row < N) {
                float v = acc[t][rr] + b;
                if (leaky) v = v >= 0.f ? v : 0.1f * v;
                if (resid) v += resid[(size_t)row * WW + col];
                if (OUT_BF16)
                    ((__hip_bfloat16*)outv)[(size_t)row * WW + col] = __float2bfloat16(v);
                else
                    ((float*)outv)[(size_t)row * WW + col] = v;
            }
        }
    }
}

extern "C" void kernel_launch(void* const* d_in, const int* in_sizes, int n_in,
                              void* d_out, int out_size, void* d_ws, size_t ws_size,
                              hipStream_t stream) {
    const float* x      = (const float*)d_in[0];
    const int*   ei     = (const int*)d_in[1];
    const float* ew     = (const float*)d_in[2];
    const int*   batch  = (const int*)d_in[3];
    const float* gnw    = (const float*)d_in[4];
    const float* gnb    = (const float*)d_in[5];
    const float* gnm    = (const float*)d_in[6];
    const float* Wrel1  = (const float*)d_in[7];
    const float* brel1  = (const float*)d_in[8];
    const float* Wroot1 = (const float*)d_in[9];
    const float* Wrel2  = (const float*)d_in[10];
    const float* brel2  = (const float*)d_in[11];
    const float* Wroot2 = (const float*)d_in[12];

    int N = in_sizes[0] / WW;
    int E = in_sizes[1] / 2;
    int P = (N + SCAN_B - 1) / SCAN_B;   // scan partial count (98 for N=100k)

    // workspace layout (all 8-byte aligned):
    // aggbf | xn | y1 (bf16 N*W each) | Wb (bf16 4*W*W) | ebuf (int2 E)
    // | deg | cursor | off (int N each) | bsum (int 256) | stats floats
    __hip_bfloat16* aggbf = (__hip_bfloat16*)d_ws;
    __hip_bfloat16* xn = aggbf + (size_t)N * WW;
    __hip_bfloat16* y1 = xn + (size_t)N * WW;
    __hip_bfloat16* Wb = y1 + (size_t)N * WW;       // [Wrel1|Wroot1|Wrel2|Wroot2]
    int2* ebuf   = (int2*)(Wb + 4 * WW * WW);
    int*  deg    = (int*)(ebuf + E);
    int*  cursor = deg + N;
    int*  off    = cursor + N;
    int*  bsum   = off + N;
    float* gsum   = (float*)(bsum + 256);
    float* gsumsq = gsum + GG * WW;
    float* gcnt   = gsumsq + GG * WW;               // GG floats
    float* scalev = gcnt + GG;
    float* shiftv = scalev + GG * WW;

    hipMemsetAsync(deg, 0, (size_t)2 * N * sizeof(int), stream);   // deg + cursor
    hipMemsetAsync(gsum, 0, (size_t)(2 * GG * WW + GG) * sizeof(float), stream);

    // ---- CSR build (once; reused by both layers) ----
    hist_kernel<<<(E + 255) / 256, 256, 0, stream>>>(ei, E, deg);
    scan_blocks<<<P, SCAN_B, 0, stream>>>(deg, N, off, bsum);
    scan_partials<<<1, 256, 0, stream>>>(bsum, P);
    add_offsets<<<P, SCAN_B, 0, stream>>>(off, bsum, N);
    place_kernel<<<(E + 255) / 256, 256, 0, stream>>>(ei, ew, off, cursor, ebuf, E);

    // ---- GraphNorm ----
    cvt_w_kernel<<<(4 * WW * WW) / 256, 256, 0, stream>>>(Wrel1, Wroot1, Wrel2, Wroot2, Wb);
    stats_kernel<<<(N + 63) / 64, 128, 0, stream>>>(x, batch, N, gsum, gsumsq, gcnt);
    finalize_kernel<<<(GG * WW + 255) / 256, 256, 0, stream>>>(
        gsum, gsumsq, gcnt, gnw, gnb, gnm, scalev, shiftv);
    normalize_kernel<<<(int)(((size_t)N * WW + 255) / 256), 256, 0, stream>>>(
        x, batch, scalev, shiftv, xn, N);

    // ---- layer 1: gather + GEMM(+bias+leaky) ----
    gather_kernel<<<(N + 3) / 4, 256, 0, stream>>>(xn, ebuf, off, deg, aggbf, N);
    gemm_kernel<true><<<(N + 63) / 64, 256, 0, stream>>>(
        aggbf, xn, Wb, Wb + WW * WW, brel1, nullptr, y1, N, 1);

    // ---- layer 2: gather + GEMM(+bias+residual) ----
    gather_kernel<<<(N + 3) / 4, 256, 0, stream>>>(y1, ebuf, off, deg, aggbf, N);
    gemm_kernel<false><<<(N + 63) / 64, 256, 0, stream>>>(
        aggbf, y1, Wb + 2 * WW * WW, Wb + 3 * WW * WW, brel2, x, d_out, N, 0);
}

// Round 4
// 487.370 us; speedup vs baseline: 1.8220x; 1.0941x over previous
//
#include <hip/hip_runtime.h>
#include <hip/hip_bf16.h>

#define WW 128
#define GG 64
#define GN_EPS 1e-5f
#define SCAN_B 1024

typedef __attribute__((ext_vector_type(8))) short short8;
typedef __attribute__((ext_vector_type(4))) float floatx4;

__device__ inline float bf2f(__hip_bfloat16 h) { return __bfloat162float(h); }

// ---------------- GraphNorm stats: per-graph sum, sumsq, count ----------------
__global__ __launch_bounds__(128) void stats_kernel(
    const float* __restrict__ x, const int* __restrict__ batch, int N,
    float* __restrict__ gsum, float* __restrict__ gsumsq, float* __restrict__ gcnt)
{
    int w = threadIdx.x;
    int row0 = blockIdx.x * 64;
    int row1 = min(row0 + 64, N);
    float s = 0.f, ss = 0.f;
    int cur = batch[row0];
    int cnt = 0;
    for (int i = row0; i < row1; ++i) {
        int g = batch[i];
        if (g != cur) {
            atomicAdd(&gsum[cur * WW + w], s);
            atomicAdd(&gsumsq[cur * WW + w], ss);
            if (w == 0) atomicAdd(&gcnt[cur], (float)cnt);
            s = 0.f; ss = 0.f; cnt = 0; cur = g;
        }
        float v = x[(size_t)i * WW + w];
        s += v; ss += v * v; ++cnt;
    }
    atomicAdd(&gsum[cur * WW + w], s);
    atomicAdd(&gsumsq[cur * WW + w], ss);
    if (w == 0) atomicAdd(&gcnt[cur], (float)cnt);
}

// ---------------- fold stats into per-(g,w) affine scale/shift ----------------
__global__ __launch_bounds__(256) void finalize_kernel(
    const float* __restrict__ gsum, const float* __restrict__ gsumsq,
    const float* __restrict__ gcnt,
    const float* __restrict__ wgt, const float* __restrict__ bias,
    const float* __restrict__ ms,
    float* __restrict__ scalev, float* __restrict__ shiftv)
{
    int idx = blockIdx.x * blockDim.x + threadIdx.x;
    if (idx >= GG * WW) return;
    int g = idx >> 7, w = idx & (WW - 1);
    float cnt = gcnt[g];
    float inv = cnt > 0.f ? 1.f / cnt : 0.f;
    float mean = gsum[idx] * inv;
    float msw = ms[w];
    float var = gsumsq[idx] * inv - mean * mean * msw * (2.f - msw);
    var = fmaxf(var, 0.f);
    float sc = wgt[w] * rsqrtf(var + GN_EPS);
    scalev[idx] = sc;
    shiftv[idx] = bias[w] - sc * msw * mean;
}

// ---------------- normalize: xn = scale*x + shift (bf16 out) ----------------
__global__ __launch_bounds__(256) void normalize_kernel(
    const float* __restrict__ x, const int* __restrict__ batch,
    const float* __restrict__ scalev, const float* __restrict__ shiftv,
    __hip_bfloat16* __restrict__ xn, int N)
{
    size_t tid = (size_t)blockIdx.x * blockDim.x + threadIdx.x;
    if (tid >= (size_t)N * WW) return;
    int row = (int)(tid >> 7);
    int w = (int)(tid & (WW - 1));
    int g = batch[row];
    float v = x[tid];
    xn[tid] = __float2bfloat16(scalev[g * WW + w] * v + shiftv[g * WW + w]);
}

// ---------------- convert fp32 weight matrices -> bf16 ----------------
__global__ __launch_bounds__(256) void cvt_w_kernel(
    const float* __restrict__ w0, const float* __restrict__ w1,
    const float* __restrict__ w2, const float* __restrict__ w3,
    __hip_bfloat16* __restrict__ dst)
{
    int idx = blockIdx.x * blockDim.x + threadIdx.x;   // 0 .. 4*16384-1
    int m = idx >> 14;
    int o = idx & 16383;
    const float* src = (m == 0) ? w0 : (m == 1) ? w1 : (m == 2) ? w2 : w3;
    dst[idx] = __float2bfloat16(src[o]);
}

// ---------------- CSR build: histogram over dst ----------------
__global__ __launch_bounds__(256) void hist_kernel(
    const int* __restrict__ ei, int E, int* __restrict__ deg)
{
    int e = blockIdx.x * 256 + threadIdx.x;
    if (e < E) atomicAdd(&deg[ei[(size_t)E + e]], 1);
}

// ---------------- hierarchical exclusive scan (3 kernels) ----------------
__global__ __launch_bounds__(SCAN_B) void scan_blocks(
    const int* __restrict__ deg, int N, int* __restrict__ off, int* __restrict__ bsum)
{
    __shared__ int s[SCAN_B];
    int t = threadIdx.x;
    int i = blockIdx.x * SCAN_B + t;
    int v = (i < N) ? deg[i] : 0;
    s[t] = v; __syncthreads();
    for (int d = 1; d < SCAN_B; d <<= 1) {
        int tmp = (t >= d) ? s[t - d] : 0;
        __syncthreads();
        s[t] += tmp;
        __syncthreads();
    }
    if (i < N) off[i] = s[t] - v;                 // block-local exclusive
    if (t == SCAN_B - 1) bsum[blockIdx.x] = s[t]; // block total
}

__global__ __launch_bounds__(256) void scan_partials(int* __restrict__ bsum, int P)
{
    __shared__ int s[256];
    int t = threadIdx.x;
    int v = (t < P) ? bsum[t] : 0;
    s[t] = v; __syncthreads();
    for (int d = 1; d < 256; d <<= 1) {
        int tmp = (t >= d) ? s[t - d] : 0;
        __syncthreads();
        s[t] += tmp;
        __syncthreads();
    }
    if (t < P) bsum[t] = s[t] - v;                // exclusive, in place
}

__global__ __launch_bounds__(SCAN_B) void add_offsets(
    int* __restrict__ off, const int* __restrict__ bsum, int N)
{
    int i = blockIdx.x * SCAN_B + threadIdx.x;
    if (i < N) off[i] += bsum[blockIdx.x];
}

// ---------------- placement: ebuf[slot] = {src, weight} bucketed by dst ------
__global__ __launch_bounds__(256) void place_kernel(
    const int* __restrict__ ei, const float* __restrict__ ew,
    const int* __restrict__ off, int* __restrict__ cursor,
    int2* __restrict__ ebuf, int E)
{
    int e = blockIdx.x * 256 + threadIdx.x;
    if (e >= E) return;
    int dst = ei[(size_t)E + e];
    int slot = off[dst] + atomicAdd(&cursor[dst], 1);
    ebuf[slot] = make_int2(ei[e], __float_as_int(ew[e]));
}

// ---------------- gather: agg[i] = sum_{e: dst=i} ew_e * feat[src_e] ----------
// one wave per node; lane handles 2 channels (bf16x2 loads). No atomics.
__global__ __launch_bounds__(256) void gather_kernel(
    const __hip_bfloat16* __restrict__ feat, const int2* __restrict__ ebuf,
    const int* __restrict__ off, const int* __restrict__ deg,
    __hip_bfloat16* __restrict__ aggbf, int N)
{
    int wave = threadIdx.x >> 6;
    int lane = threadIdx.x & 63;
    int node = blockIdx.x * 4 + wave;
    if (node >= N) return;
    int start = off[node];
    int d = deg[node];
    float ax = 0.f, ay = 0.f;
    for (int k = 0; k < d; ++k) {
        int2 p = ebuf[start + k];                      // lane-uniform, broadcast
        float wt = __int_as_float(p.y);
        __hip_bfloat162 v = ((const __hip_bfloat162*)(feat + (size_t)p.x * WW))[lane];
        ax += wt * __bfloat162float(v.x);
        ay += wt * __bfloat162float(v.y);
    }
    __hip_bfloat162 o;
    o.x = __float2bfloat16(ax);
    o.y = __float2bfloat16(ay);
    ((__hip_bfloat162*)(aggbf + (size_t)node * WW))[lane] = o;
}

// ---------------- fused GEMM v2: persistent-W register caching ----------------
// y = act([A1|A2] @ [Wrel;Wroot]^T + b) (+resid). K=256.
// Wave owns 2 col-tiles (32 cols); 4 waves cover 128 cols. W fragments (8 kc x
// 2 t = 256 B/lane = 64 VGPRs) loaded ONCE, reused across all row tiles
// (grid-stride). Register blocking R=4 x T=2: per kc only 4 A-loads feed 8
// MFMAs (vs 9 loads / 8 MFMAs before, and no per-wave W re-reads from L2).
// C/D layout: col=lane&15, row=(lane>>4)*4+reg (m89-verified).
template <bool OUT_BF16>
__global__ __launch_bounds__(256) void gemm_kernel(
    const __hip_bfloat16* __restrict__ A1, const __hip_bfloat16* __restrict__ A2,
    const __hip_bfloat16* __restrict__ Wrel, const __hip_bfloat16* __restrict__ Wroot,
    const float* __restrict__ bias, const float* __restrict__ resid,
    void* __restrict__ outv, int N, int leaky, int ntiles)
{
    int wave = threadIdx.x >> 6;
    int lane = threadIdx.x & 63;
    int q = lane >> 4;
    int r16 = lane & 15;

    // persistent W fragments [kc][tt]
    short8 wf[8][2];
#pragma unroll
    for (int kc = 0; kc < 8; ++kc) {
        const __hip_bfloat16* Wsel = (kc < 4) ? Wrel : Wroot;
        int koff = (kc & 3) * 32 + q * 8;
#pragma unroll
        for (int tt = 0; tt < 2; ++tt) {
            int col = (wave * 2 + tt) * 16 + r16;
            wf[kc][tt] = *(const short8*)(Wsel + ((size_t)col * WW + koff));
        }
    }
    float bcol[2];
#pragma unroll
    for (int tt = 0; tt < 2; ++tt) bcol[tt] = bias[(wave * 2 + tt) * 16 + r16];

    for (int tile = blockIdx.x; tile < ntiles; tile += gridDim.x) {
        int rb = tile * 64;
        floatx4 acc[4][2];
#pragma unroll
        for (int r = 0; r < 4; ++r)
#pragma unroll
            for (int tt = 0; tt < 2; ++tt) acc[r][tt] = (floatx4){0.f, 0.f, 0.f, 0.f};

#pragma unroll
        for (int kc = 0; kc < 8; ++kc) {
            const __hip_bfloat16* Asel = (kc < 4) ? A1 : A2;
            int koff = (kc & 3) * 32 + q * 8;
            short8 af[4];
#pragma unroll
            for (int r = 0; r < 4; ++r) {
                int ar = rb + r * 16 + r16;
                if (ar >= N) ar = N - 1;       // clamp loads; stores masked
                af[r] = *(const short8*)(Asel + ((size_t)ar * WW + koff));
            }
#pragma unroll
            for (int r = 0; r < 4; ++r)
#pragma unroll
                for (int tt = 0; tt < 2; ++tt)
                    acc[r][tt] = __builtin_amdgcn_mfma_f32_16x16x32_bf16(
                        af[r], wf[kc][tt], acc[r][tt], 0, 0, 0);
        }

#pragma unroll
        for (int tt = 0; tt < 2; ++tt) {
            int col = (wave * 2 + tt) * 16 + r16;
#pragma unroll
            for (int r = 0; r < 4; ++r)
#pragma unroll
                for (int rr = 0; rr < 4; ++rr) {
                    int row = rb + r * 16 + q * 4 + rr;
                    if (row < N) {
                        float v = acc[r][tt][rr] + bcol[tt];
                        if (leaky) v = v >= 0.f ? v : 0.1f * v;
                        if (resid) v += resid[(size_t)row * WW + col];
                        if (OUT_BF16)
                            ((__hip_bfloat16*)outv)[(size_t)row * WW + col] = __float2bfloat16(v);
                        else
                            ((float*)outv)[(size_t)row * WW + col] = v;
                    }
                }
        }
    }
}

extern "C" void kernel_launch(void* const* d_in, const int* in_sizes, int n_in,
                              void* d_out, int out_size, void* d_ws, size_t ws_size,
                              hipStream_t stream) {
    const float* x      = (const float*)d_in[0];
    const int*   ei     = (const int*)d_in[1];
    const float* ew     = (const float*)d_in[2];
    const int*   batch  = (const int*)d_in[3];
    const float* gnw    = (const float*)d_in[4];
    const float* gnb    = (const float*)d_in[5];
    const float* gnm    = (const float*)d_in[6];
    const float* Wrel1  = (const float*)d_in[7];
    const float* brel1  = (const float*)d_in[8];
    const float* Wroot1 = (const float*)d_in[9];
    const float* Wrel2  = (const float*)d_in[10];
    const float* brel2  = (const float*)d_in[11];
    const float* Wroot2 = (const float*)d_in[12];

    int N = in_sizes[0] / WW;
    int E = in_sizes[1] / 2;
    int P = (N + SCAN_B - 1) / SCAN_B;   // scan partial count (98 for N=100k)
    int ntiles = (N + 63) / 64;

    // workspace layout (8-byte aligned):
    // aggbf | xn | y1 (bf16 N*W each) | Wb (bf16 4*W*W) | ebuf (int2 E)
    // | deg | cursor | gsum | gsumsq | gcnt | scalev | shiftv | off | bsum
    __hip_bfloat16* aggbf = (__hip_bfloat16*)d_ws;
    __hip_bfloat16* xn = aggbf + (size_t)N * WW;
    __hip_bfloat16* y1 = xn + (size_t)N * WW;
    __hip_bfloat16* Wb = y1 + (size_t)N * WW;       // [Wrel1|Wroot1|Wrel2|Wroot2]
    int2* ebuf   = (int2*)(Wb + 4 * WW * WW);
    int*  deg    = (int*)(ebuf + E);
    int*  cursor = deg + N;
    float* gsum   = (float*)(cursor + N);
    float* gsumsq = gsum + GG * WW;
    float* gcnt   = gsumsq + GG * WW;               // GG floats
    float* scalev = gcnt + GG;
    float* shiftv = scalev + GG * WW;
    int*  off    = (int*)(shiftv + GG * WW);
    int*  bsum   = off + N;

    // one memset covers deg, cursor, gsum, gsumsq, gcnt (contiguous)
    hipMemsetAsync(deg, 0, ((size_t)2 * N + 2 * GG * WW + GG) * sizeof(int), stream);

    // ---- CSR build (once; reused by both layers) ----
    hist_kernel<<<(E + 255) / 256, 256, 0, stream>>>(ei, E, deg);
    scan_blocks<<<P, SCAN_B, 0, stream>>>(deg, N, off, bsum);
    scan_partials<<<1, 256, 0, stream>>>(bsum, P);
    add_offsets<<<P, SCAN_B, 0, stream>>>(off, bsum, N);
    place_kernel<<<(E + 255) / 256, 256, 0, stream>>>(ei, ew, off, cursor, ebuf, E);

    // ---- GraphNorm ----
    cvt_w_kernel<<<(4 * WW * WW) / 256, 256, 0, stream>>>(Wrel1, Wroot1, Wrel2, Wroot2, Wb);
    stats_kernel<<<(N + 63) / 64, 128, 0, stream>>>(x, batch, N, gsum, gsumsq, gcnt);
    finalize_kernel<<<(GG * WW + 255) / 256, 256, 0, stream>>>(
        gsum, gsumsq, gcnt, gnw, gnb, gnm, scalev, shiftv);
    normalize_kernel<<<(int)(((size_t)N * WW + 255) / 256), 256, 0, stream>>>(
        x, batch, scalev, shiftv, xn, N);

    // ---- layer 1: gather + GEMM(+bias+leaky) ----
    gather_kernel<<<(N + 3) / 4, 256, 0, stream>>>(xn, ebuf, off, deg, aggbf, N);
    gemm_kernel<true><<<512, 256, 0, stream>>>(
        aggbf, xn, Wb, Wb + WW * WW, brel1, nullptr, y1, N, 1, ntiles);

    // ---- layer 2: gather + GEMM(+bias+residual) ----
    gather_kernel<<<(N + 3) / 4, 256, 0, stream>>>(y1, ebuf, off, deg, aggbf, N);
    gemm_kernel<false><<<512, 256, 0, stream>>>(
        aggbf, y1, Wb + 2 * WW * WW, Wb + 3 * WW * WW, brel2, x, d_out, N, 0, ntiles);
}

// Round 6
// 433.861 us; speedup vs baseline: 2.0467x; 1.1233x over previous
//
#include <hip/hip_runtime.h>
#include <hip/hip_bf16.h>

#define WW 128
#define GG 64
#define GN_EPS 1e-5f
#define SCAN_B 1024

typedef __attribute__((ext_vector_type(8))) short short8;
typedef __attribute__((ext_vector_type(4))) float floatx4;

__device__ inline float bf2f(__hip_bfloat16 h) { return __bfloat162float(h); }

// ---------------- GraphNorm stats: per-graph sum, sumsq, count ----------------
__global__ __launch_bounds__(128) void stats_kernel(
    const float* __restrict__ x, const int* __restrict__ batch, int N,
    float* __restrict__ gsum, float* __restrict__ gsumsq, float* __restrict__ gcnt)
{
    int w = threadIdx.x;
    int row0 = blockIdx.x * 64;
    int row1 = min(row0 + 64, N);
    float s = 0.f, ss = 0.f;
    int cur = batch[row0];
    int cnt = 0;
    for (int i = row0; i < row1; ++i) {
        int g = batch[i];
        if (g != cur) {
            atomicAdd(&gsum[cur * WW + w], s);
            atomicAdd(&gsumsq[cur * WW + w], ss);
            if (w == 0) atomicAdd(&gcnt[cur], (float)cnt);
            s = 0.f; ss = 0.f; cnt = 0; cur = g;
        }
        float v = x[(size_t)i * WW + w];
        s += v; ss += v * v; ++cnt;
    }
    atomicAdd(&gsum[cur * WW + w], s);
    atomicAdd(&gsumsq[cur * WW + w], ss);
    if (w == 0) atomicAdd(&gcnt[cur], (float)cnt);
}

// ---------------- fold stats into per-(g,w) affine scale/shift ----------------
__global__ __launch_bounds__(256) void finalize_kernel(
    const float* __restrict__ gsum, const float* __restrict__ gsumsq,
    const float* __restrict__ gcnt,
    const float* __restrict__ wgt, const float* __restrict__ bias,
    const float* __restrict__ ms,
    float* __restrict__ scalev, float* __restrict__ shiftv)
{
    int idx = blockIdx.x * blockDim.x + threadIdx.x;
    if (idx >= GG * WW) return;
    int g = idx >> 7, w = idx & (WW - 1);
    float cnt = gcnt[g];
    float inv = cnt > 0.f ? 1.f / cnt : 0.f;
    float mean = gsum[idx] * inv;
    float msw = ms[w];
    float var = gsumsq[idx] * inv - mean * mean * msw * (2.f - msw);
    var = fmaxf(var, 0.f);
    float sc = wgt[w] * rsqrtf(var + GN_EPS);
    scalev[idx] = sc;
    shiftv[idx] = bias[w] - sc * msw * mean;
}

// ---------------- normalize: xn = scale*x + shift (bf16 out) ----------------
__global__ __launch_bounds__(256) void normalize_kernel(
    const float* __restrict__ x, const int* __restrict__ batch,
    const float* __restrict__ scalev, const float* __restrict__ shiftv,
    __hip_bfloat16* __restrict__ xn, int N)
{
    size_t tid = (size_t)blockIdx.x * blockDim.x + threadIdx.x;
    if (tid >= (size_t)N * WW) return;
    int row = (int)(tid >> 7);
    int w = (int)(tid & (WW - 1));
    int g = batch[row];
    float v = x[tid];
    xn[tid] = __float2bfloat16(scalev[g * WW + w] * v + shiftv[g * WW + w]);
}

// ---------------- convert fp32 weight matrices -> bf16 ----------------
__global__ __launch_bounds__(256) void cvt_w_kernel(
    const float* __restrict__ w0, const float* __restrict__ w1,
    const float* __restrict__ w2, const float* __restrict__ w3,
    __hip_bfloat16* __restrict__ dst)
{
    int idx = blockIdx.x * blockDim.x + threadIdx.x;   // 0 .. 4*16384-1
    int m = idx >> 14;
    int o = idx & 16383;
    const float* src = (m == 0) ? w0 : (m == 1) ? w1 : (m == 2) ? w2 : w3;
    dst[idx] = __float2bfloat16(src[o]);
}

// ---------------- CSR build: histogram over dst ----------------
__global__ __launch_bounds__(256) void hist_kernel(
    const int* __restrict__ ei, int E, int* __restrict__ deg)
{
    int e = blockIdx.x * 256 + threadIdx.x;
    if (e < E) atomicAdd(&deg[ei[(size_t)E + e]], 1);
}

// ---------------- hierarchical exclusive scan (3 kernels) ----------------
__global__ __launch_bounds__(SCAN_B) void scan_blocks(
    const int* __restrict__ deg, int N, int* __restrict__ off, int* __restrict__ bsum)
{
    __shared__ int s[SCAN_B];
    int t = threadIdx.x;
    int i = blockIdx.x * SCAN_B + t;
    int v = (i < N) ? deg[i] : 0;
    s[t] = v; __syncthreads();
    for (int d = 1; d < SCAN_B; d <<= 1) {
        int tmp = (t >= d) ? s[t - d] : 0;
        __syncthreads();
        s[t] += tmp;
        __syncthreads();
    }
    if (i < N) off[i] = s[t] - v;                 // block-local exclusive
    if (t == SCAN_B - 1) bsum[blockIdx.x] = s[t]; // block total
}

__global__ __launch_bounds__(256) void scan_partials(int* __restrict__ bsum, int P)
{
    __shared__ int s[256];
    int t = threadIdx.x;
    int v = (t < P) ? bsum[t] : 0;
    s[t] = v; __syncthreads();
    for (int d = 1; d < 256; d <<= 1) {
        int tmp = (t >= d) ? s[t - d] : 0;
        __syncthreads();
        s[t] += tmp;
        __syncthreads();
    }
    if (t < P) bsum[t] = s[t] - v;                // exclusive, in place
}

__global__ __launch_bounds__(SCAN_B) void add_offsets(
    int* __restrict__ off, const int* __restrict__ bsum, int N)
{
    int i = blockIdx.x * SCAN_B + threadIdx.x;
    if (i < N) off[i] += bsum[blockIdx.x];
}

// ---------------- placement: ebuf[slot] = {src, weight} bucketed by dst ------
__global__ __launch_bounds__(256) void place_kernel(
    const int* __restrict__ ei, const float* __restrict__ ew,
    const int* __restrict__ off, int* __restrict__ cursor,
    int2* __restrict__ ebuf, int E)
{
    int e = blockIdx.x * 256 + threadIdx.x;
    if (e >= E) return;
    int dst = ei[(size_t)E + e];
    int slot = off[dst] + atomicAdd(&cursor[dst], 1);
    ebuf[slot] = make_int2(ei[e], __float_as_int(ew[e]));
}

// ---------------- gather v4: R4 structure + manual 4-deep unroll ----------
// One wave per node; lane owns 2 channels (bf16x2). Per main-loop iteration,
// 4 independent ebuf reads then 4 independent row loads are in flight before
// any FMA consumes them (4x memory-level parallelism vs R4's serial walk).
// No cross-lane ops. Tail serial. Arithmetic == R4 (verified absmax 0.125),
// modulo 4-way partial-sum reassociation.
__global__ __launch_bounds__(256) void gather_kernel(
    const __hip_bfloat16* __restrict__ feat, const int2* __restrict__ ebuf,
    const int* __restrict__ off, const int* __restrict__ deg,
    __hip_bfloat16* __restrict__ aggbf, int N)
{
    int wave = threadIdx.x >> 6;
    int lane = threadIdx.x & 63;
    int node = blockIdx.x * 4 + wave;
    if (node >= N) return;
    int start = off[node];
    int d = deg[node];
    const __hip_bfloat162* f2 = (const __hip_bfloat162*)feat;

    float ax0 = 0.f, ay0 = 0.f, ax1 = 0.f, ay1 = 0.f;
    float ax2 = 0.f, ay2 = 0.f, ax3 = 0.f, ay3 = 0.f;
    int k = 0;
    for (; k + 4 <= d; k += 4) {
        int2 p0 = ebuf[start + k + 0];
        int2 p1 = ebuf[start + k + 1];
        int2 p2 = ebuf[start + k + 2];
        int2 p3 = ebuf[start + k + 3];
        __hip_bfloat162 v0 = f2[(size_t)p0.x * 64 + lane];
        __hip_bfloat162 v1 = f2[(size_t)p1.x * 64 + lane];
        __hip_bfloat162 v2 = f2[(size_t)p2.x * 64 + lane];
        __hip_bfloat162 v3 = f2[(size_t)p3.x * 64 + lane];
        float w0 = __int_as_float(p0.y);
        float w1 = __int_as_float(p1.y);
        float w2 = __int_as_float(p2.y);
        float w3 = __int_as_float(p3.y);
        ax0 += w0 * bf2f(v0.x); ay0 += w0 * bf2f(v0.y);
        ax1 += w1 * bf2f(v1.x); ay1 += w1 * bf2f(v1.y);
        ax2 += w2 * bf2f(v2.x); ay2 += w2 * bf2f(v2.y);
        ax3 += w3 * bf2f(v3.x); ay3 += w3 * bf2f(v3.y);
    }
    for (; k < d; ++k) {
        int2 p = ebuf[start + k];
        float wt = __int_as_float(p.y);
        __hip_bfloat162 v = f2[(size_t)p.x * 64 + lane];
        ax0 += wt * bf2f(v.x);
        ay0 += wt * bf2f(v.y);
    }
    float ax = (ax0 + ax1) + (ax2 + ax3);
    float ay = (ay0 + ay1) + (ay2 + ay3);

    __hip_bfloat162 o;
    o.x = __float2bfloat16(ax);
    o.y = __float2bfloat16(ay);
    ((__hip_bfloat162*)(aggbf + (size_t)node * WW))[lane] = o;
}

// ---------------- fused GEMM: persistent-W register caching ----------------
// y = act([A1|A2] @ [Wrel;Wroot]^T + b) (+resid). K=256. Wave owns 32 cols;
// W fragments loaded once per block; R=4 row-blocking; one 64-row tile/block.
// C/D layout: col=lane&15, row=(lane>>4)*4+reg (m89-verified).
template <bool OUT_BF16>
__global__ __launch_bounds__(256) void gemm_kernel(
    const __hip_bfloat16* __restrict__ A1, const __hip_bfloat16* __restrict__ A2,
    const __hip_bfloat16* __restrict__ Wrel, const __hip_bfloat16* __restrict__ Wroot,
    const float* __restrict__ bias, const float* __restrict__ resid,
    void* __restrict__ outv, int N, int leaky, int ntiles)
{
    int wave = threadIdx.x >> 6;
    int lane = threadIdx.x & 63;
    int q = lane >> 4;
    int r16 = lane & 15;

    // persistent W fragments [kc][tt]
    short8 wf[8][2];
#pragma unroll
    for (int kc = 0; kc < 8; ++kc) {
        const __hip_bfloat16* Wsel = (kc < 4) ? Wrel : Wroot;
        int koff = (kc & 3) * 32 + q * 8;
#pragma unroll
        for (int tt = 0; tt < 2; ++tt) {
            int col = (wave * 2 + tt) * 16 + r16;
            wf[kc][tt] = *(const short8*)(Wsel + ((size_t)col * WW + koff));
        }
    }
    float bcol[2];
#pragma unroll
    for (int tt = 0; tt < 2; ++tt) bcol[tt] = bias[(wave * 2 + tt) * 16 + r16];

    for (int tile = blockIdx.x; tile < ntiles; tile += gridDim.x) {
        int rb = tile * 64;
        floatx4 acc[4][2];
#pragma unroll
        for (int r = 0; r < 4; ++r)
#pragma unroll
            for (int tt = 0; tt < 2; ++tt) acc[r][tt] = (floatx4){0.f, 0.f, 0.f, 0.f};

#pragma unroll
        for (int kc = 0; kc < 8; ++kc) {
            const __hip_bfloat16* Asel = (kc < 4) ? A1 : A2;
            int koff = (kc & 3) * 32 + q * 8;
            short8 af[4];
#pragma unroll
            for (int r = 0; r < 4; ++r) {
                int ar = rb + r * 16 + r16;
                if (ar >= N) ar = N - 1;       // clamp loads; stores masked
                af[r] = *(const short8*)(Asel + ((size_t)ar * WW + koff));
            }
#pragma unroll
            for (int r = 0; r < 4; ++r)
#pragma unroll
                for (int tt = 0; tt < 2; ++tt)
                    acc[r][tt] = __builtin_amdgcn_mfma_f32_16x16x32_bf16(
                        af[r], wf[kc][tt], acc[r][tt], 0, 0, 0);
        }

#pragma unroll
        for (int tt = 0; tt < 2; ++tt) {
            int col = (wave * 2 + tt) * 16 + r16;
#pragma unroll
            for (int r = 0; r < 4; ++r)
#pragma unroll
                for (int rr = 0; rr < 4; ++rr) {
                    int row = rb + r * 16 + q * 4 + rr;
                    if (row < N) {
                        float v = acc[r][tt][rr] + bcol[tt];
                        if (leaky) v = v >= 0.f ? v : 0.1f * v;
                        if (resid) v += resid[(size_t)row * WW + col];
                        if (OUT_BF16)
                            ((__hip_bfloat16*)outv)[(size_t)row * WW + col] = __float2bfloat16(v);
                        else
                            ((float*)outv)[(size_t)row * WW + col] = v;
                    }
                }
        }
    }
}

extern "C" void kernel_launch(void* const* d_in, const int* in_sizes, int n_in,
                              void* d_out, int out_size, void* d_ws, size_t ws_size,
                              hipStream_t stream) {
    const float* x      = (const float*)d_in[0];
    const int*   ei     = (const int*)d_in[1];
    const float* ew     = (const float*)d_in[2];
    const int*   batch  = (const int*)d_in[3];
    const float* gnw    = (const float*)d_in[4];
    const float* gnb    = (const float*)d_in[5];
    const float* gnm    = (const float*)d_in[6];
    const float* Wrel1  = (const float*)d_in[7];
    const float* brel1  = (const float*)d_in[8];
    const float* Wroot1 = (const float*)d_in[9];
    const float* Wrel2  = (const float*)d_in[10];
    const float* brel2  = (const float*)d_in[11];
    const float* Wroot2 = (const float*)d_in[12];

    int N = in_sizes[0] / WW;
    int E = in_sizes[1] / 2;
    int P = (N + SCAN_B - 1) / SCAN_B;   // scan partial count (98 for N=100k)
    int ntiles = (N + 63) / 64;

    // workspace layout (8-byte aligned):
    // aggbf | xn | y1 (bf16 N*W each) | Wb (bf16 4*W*W) | ebuf (int2 E)
    // | deg | cursor | gsum | gsumsq | gcnt | scalev | shiftv | off | bsum
    __hip_bfloat16* aggbf = (__hip_bfloat16*)d_ws;
    __hip_bfloat16* xn = aggbf + (size_t)N * WW;
    __hip_bfloat16* y1 = xn + (size_t)N * WW;
    __hip_bfloat16* Wb = y1 + (size_t)N * WW;       // [Wrel1|Wroot1|Wrel2|Wroot2]
    int2* ebuf   = (int2*)(Wb + 4 * WW * WW);
    int*  deg    = (int*)(ebuf + E);
    int*  cursor = deg + N;
    float* gsum   = (float*)(cursor + N);
    float* gsumsq = gsum + GG * WW;
    float* gcnt   = gsumsq + GG * WW;               // GG floats
    float* scalev = gcnt + GG;
    float* shiftv = scalev + GG * WW;
    int*  off    = (int*)(shiftv + GG * WW);
    int*  bsum   = off + N;

    // one memset covers deg, cursor, gsum, gsumsq, gcnt (contiguous)
    hipMemsetAsync(deg, 0, ((size_t)2 * N + 2 * GG * WW + GG) * sizeof(int), stream);

    // ---- CSR build (once; reused by both layers) ----
    hist_kernel<<<(E + 255) / 256, 256, 0, stream>>>(ei, E, deg);
    scan_blocks<<<P, SCAN_B, 0, stream>>>(deg, N, off, bsum);
    scan_partials<<<1, 256, 0, stream>>>(bsum, P);
    add_offsets<<<P, SCAN_B, 0, stream>>>(off, bsum, N);
    place_kernel<<<(E + 255) / 256, 256, 0, stream>>>(ei, ew, off, cursor, ebuf, E);

    // ---- GraphNorm ----
    cvt_w_kernel<<<(4 * WW * WW) / 256, 256, 0, stream>>>(Wrel1, Wroot1, Wrel2, Wroot2, Wb);
    stats_kernel<<<(N + 63) / 64, 128, 0, stream>>>(x, batch, N, gsum, gsumsq, gcnt);
    finalize_kernel<<<(GG * WW + 255) / 256, 256, 0, stream>>>(
        gsum, gsumsq, gcnt, gnw, gnb, gnm, scalev, shiftv);
    normalize_kernel<<<(int)(((size_t)N * WW + 255) / 256), 256, 0, stream>>>(
        x, batch, scalev, shiftv, xn, N);

    // ---- layer 1: gather + GEMM(+bias+leaky) ----
    gather_kernel<<<(N + 3) / 4, 256, 0, stream>>>(xn, ebuf, off, deg, aggbf, N);
    gemm_kernel<true><<<ntiles, 256, 0, stream>>>(
        aggbf, xn, Wb, Wb + WW * WW, brel1, nullptr, y1, N, 1, ntiles);

    // ---- layer 2: gather + GEMM(+bias+residual) ----
    gather_kernel<<<(N + 3) / 4, 256, 0, stream>>>(y1, ebuf, off, deg, aggbf, N);
    gemm_kernel<false><<<ntiles, 256, 0, stream>>>(
        aggbf, y1, Wb + 2 * WW * WW, Wb + 3 * WW * WW, brel2, x, d_out, N, 0, ntiles);
}